// Round 8
// baseline (456.992 us; speedup 1.0000x reference)
//
#include <hip/hip_runtime.h>

#define FD 128
#define CAP 64   // max degree capacity == wave width; Binomial(1.6M,1e-5) max ~45
#define BSH 8    // bin shift: 256 nodes per bin
#define MAXNB 512

typedef __attribute__((ext_vector_type(8))) short bf16x8;
typedef __attribute__((ext_vector_type(4))) float f32x4;

__device__ __forceinline__ float bflo(unsigned v) { return __uint_as_float(v << 16); }
__device__ __forceinline__ float bfhi(unsigned v) { return __uint_as_float(v & 0xffff0000u); }
__device__ __forceinline__ unsigned short f2b(float f) {  // fp32 -> bf16 RNE
  unsigned u = __float_as_uint(f);
  return (unsigned short)((u + 0x7fffu + ((u >> 16) & 1u)) >> 16);
}
__device__ __forceinline__ unsigned pack2(float x, float y) {
  return (unsigned)f2b(x) | ((unsigned)f2b(y) << 16);
}

// ---------------- phase A: per-bin edge histogram ----------------
__global__ __launch_bounds__(256) void k_hist(const int* __restrict__ src,
                                              const int* __restrict__ dst,
                                              int* __restrict__ binCnt, int E, int n, int NB) {
  __shared__ int lh[MAXNB];
  for (int i = threadIdx.x; i < NB; i += 256) lh[i] = 0;
  __syncthreads();
  for (int e = blockIdx.x * 256 + threadIdx.x; e < E; e += gridDim.x * 256) {
    unsigned s = (unsigned)src[e], d = (unsigned)dst[e];
    if (s < (unsigned)n && d < (unsigned)n) atomicAdd(&lh[d >> BSH], 1);
  }
  __syncthreads();
  for (int i = threadIdx.x; i < NB; i += 256) {
    int c = lh[i];
    if (c) atomicAdd(&binCnt[i], c);
  }
}

// ---------------- phase B: exclusive prefix sum over bins ----------------
__global__ __launch_bounds__(512) void k_scan(const int* __restrict__ binCnt,
                                              int* __restrict__ binStart,
                                              int* __restrict__ binCur, int NB) {
  __shared__ int buf[512];
  int t = threadIdx.x;
  int v0 = (t < NB) ? binCnt[t] : 0;
  buf[t] = v0;
  __syncthreads();
  for (int off = 1; off < 512; off <<= 1) {
    int v = (t >= off) ? buf[t - off] : 0;
    __syncthreads();
    buf[t] += v;
    __syncthreads();
  }
  if (t < NB) {
    int ex = buf[t] - v0;
    binStart[t] = ex;
    binCur[t] = ex;
  }
}

// ---------------- phase C: scatter edges into bin-contiguous pair array ----------------
__global__ __launch_bounds__(256) void k_binscatter(const int* __restrict__ src,
                                                    const int* __restrict__ dst,
                                                    int* __restrict__ binCur,
                                                    uint2* __restrict__ binned, int E, int n, int NB) {
  __shared__ int lcnt[MAXNB], lbase[MAXNB];
  const int CH = 4096;
  int e0 = blockIdx.x * CH;
  for (int i = threadIdx.x; i < NB; i += 256) lcnt[i] = 0;
  __syncthreads();
  int se[16], de[16];
#pragma unroll
  for (int k = 0; k < 16; ++k) {
    int e = e0 + k * 256 + threadIdx.x;
    int ok = e < E;
    unsigned s = ok ? (unsigned)src[e] : 0u;
    unsigned d = ok ? (unsigned)dst[e] : 0u;
    ok = ok && s < (unsigned)n && d < (unsigned)n;
    se[k] = (int)s;
    de[k] = ok ? (int)d : -1;
    if (ok) atomicAdd(&lcnt[d >> BSH], 1);
  }
  __syncthreads();
  for (int i = threadIdx.x; i < NB; i += 256) {
    int c = lcnt[i];
    lbase[i] = c ? atomicAdd(&binCur[i], c) : 0;
    lcnt[i] = 0;
  }
  __syncthreads();
#pragma unroll
  for (int k = 0; k < 16; ++k) {
    if (de[k] >= 0) {
      int b = de[k] >> BSH;
      int p = lbase[b] + atomicAdd(&lcnt[b], 1);
      binned[p] = make_uint2((unsigned)se[k], (unsigned)de[k]);
    }
  }
}

// ---------------- phase D: build idx/cnt, one block per bin ----------------
__global__ __launch_bounds__(256) void k_bucket2(const uint2* __restrict__ binned,
                                                 const int* __restrict__ binStart,
                                                 const int* __restrict__ binCnt,
                                                 int* __restrict__ cnt,
                                                 int* __restrict__ idx, int n) {
  __shared__ int lcnt[256];
  int bin = blockIdx.x;
  int base = bin << BSH;
  lcnt[threadIdx.x] = 0;
  __syncthreads();
  int s0 = binStart[bin], c0 = binCnt[bin];
  for (int i = threadIdx.x; i < c0; i += 256) {
    uint2 pr = binned[s0 + i];
    int p = atomicAdd(&lcnt[pr.y & 255], 1);
    if (p < CAP) idx[(size_t)pr.y * CAP + p] = (int)pr.x;
  }
  __syncthreads();
  int d = base + threadIdx.x;
  if (d < n) cnt[d] = lcnt[threadIdx.x];
}

// ---------------- fp32 -> bf16 cast of x ----------------
__global__ __launch_bounds__(256) void k_xcast(const float4* __restrict__ x,
                                               unsigned short* __restrict__ xb, int total4) {
  int i = blockIdx.x * 256 + threadIdx.x;
  if (i >= total4) return;
  float4 v = x[i];
  *(uint2*)&xb[(size_t)i * 4] = make_uint2(pack2(v.x, v.y), pack2(v.z, v.w));
}

// ---------------- combined weight repack + sentinel zeroing ----------------
// blocks [0,64): W1 -> w1f (K=256)   [64,128): W2 -> w2f (K=256)
// [128,224): concat(W0,Wp0,Wp1) -> wcf (K=384)   [224,288): WT -> wtf (K=256)
// block 288: zero xb sentinel row; 289: zero f1b sentinel row.
// frag layout: Wf[(ct*nkt + kt)*64 + lane][8]; B[k][n]: n=ct*16+(lane&15), k=kt*32+(lane>>4)*8+j
__global__ __launch_bounds__(64) void k_prep(const float* __restrict__ W1,
                                             const float* __restrict__ W2,
                                             const float* __restrict__ W0,
                                             const float* __restrict__ WpA,
                                             const float* __restrict__ WpB,
                                             const float* __restrict__ WT,
                                             unsigned short* __restrict__ w1f,
                                             unsigned short* __restrict__ w2f,
                                             unsigned short* __restrict__ wcf,
                                             unsigned short* __restrict__ wtf,
                                             unsigned* __restrict__ sent_x,
                                             unsigned* __restrict__ sent_f) {
  int b = blockIdx.x;
  int lane = threadIdx.x;
  if (b >= 288) {  // sentinel zero rows: 128 bf16 = 64 uints
    unsigned* d = (b == 288) ? sent_x : sent_f;
    d[lane] = 0u;
    return;
  }
  const float* srcW;
  unsigned short* Wf;
  int nkt, bb;
  if (b < 64)       { srcW = W1; Wf = w1f; nkt = 8;  bb = b; }
  else if (b < 128) { srcW = W2; Wf = w2f; nkt = 8;  bb = b - 64; }
  else if (b < 224) { srcW = W0; Wf = wcf; nkt = 12; bb = b - 128; }
  else              { srcW = WT; Wf = wtf; nkt = 8;  bb = b - 224; }
  int ct = bb % 8, kt = bb / 8;
  int ktl = kt;
  if (nkt == 12) {  // K-concat of three 128x128 matrices
    srcW = kt < 4 ? W0 : (kt < 8 ? WpA : WpB);
    ktl = kt & 3;
  }
  int m = lane & 15, q = lane >> 4;
  int nn = ct * 16 + m;
  int k0 = ktl * 32 + q * 8;
  unsigned short tmp[8];
#pragma unroll
  for (int j = 0; j < 8; ++j) tmp[j] = f2b(srcW[(size_t)(k0 + j) * FD + nn]);
  unsigned short* dst = Wf + ((size_t)(ct * nkt + kt) * 64 + lane) * 8;
  *(uint4*)dst = *(uint4*)tmp;
}

// ---------------- fused gather-mean + SAGE layer (bf16 MFMA) ----------------
// hb has n+1 rows; row n is all-zero (sentinel). 32 rows/block, 8 rows/wave.
// Gather: one dwordx4 per 4 neighbor rows — lane covers features 8*(lane&15)..+7
// of neighbor slot (lane>>4); padded slots pre-mapped to sentinel at prefetch.
// Epilogue: rows < split -> bf16 outb; rows >= split -> fp32 outf.
__global__ __launch_bounds__(256, 4) void k_sage(const unsigned* __restrict__ hb,  // bf16 [n+1][128] as uint[.][64]
                                                 const int* __restrict__ cnt,
                                                 const int* __restrict__ idx,
                                                 const unsigned short* __restrict__ Wf,  // [8][8][64][8]
                                                 float* __restrict__ outf,
                                                 unsigned short* __restrict__ outb,
                                                 int n, int split) {
  __shared__ unsigned short sa[32][264];
  int tid = threadIdx.x;
  int lane = tid & 63, wv = tid >> 6;
  int rowBase = blockIdx.x * 32;

  // stage self rows (k = 0..127)
  for (int i = tid; i < 32 * 64; i += 256) {
    int r = i >> 6, cp = i & 63;
    int gr = rowBase + r;
    unsigned v = (gr < n) ? hb[(size_t)gr * 64 + cp] : 0u;
    *(unsigned*)&sa[r][cp * 2] = v;
  }

  // ---- gather-mean: 8 rows/wave, 4 neighbors per load ----
  int rbase = wv * 8;
  const int* ip = idx + (size_t)(rowBase + rbase) * CAP;
  int slot = lane >> 4;   // neighbor slot 0..3
  int fq = lane & 15;     // feature quad: features 8*fq .. 8*fq+7
  int vidx[8], c[8];
  int maxc = 0;
#pragma unroll
  for (int j = 0; j < 8; ++j) {
    int gr = rowBase + rbase + j;
    int cj = (gr < n) ? min(cnt[gr], CAP) : 0;
    cj = __builtin_amdgcn_readfirstlane(cj);
    c[j] = cj;
    maxc = max(maxc, cj);
    int vi = ip[j * CAP + lane];            // coalesced 256 B prefetch
    vidx[j] = (lane < cj) ? vi : n;         // padded slots -> sentinel row
  }
  float acc8[8][8];
#pragma unroll
  for (int j = 0; j < 8; ++j)
#pragma unroll
    for (int t = 0; t < 8; ++t) acc8[j][t] = 0.f;

  for (int e0 = 0; e0 < maxc; e0 += 4) {  // wave-uniform bound
#pragma unroll
    for (int j = 0; j < 8; ++j) {
      int s = __shfl(vidx[j], e0 + slot, 64);         // ds_bpermute broadcast
      uint4 v = *(const uint4*)&hb[(size_t)s * 64 + fq * 4];  // 16 B of one row
      acc8[j][0] += bflo(v.x); acc8[j][1] += bfhi(v.x);
      acc8[j][2] += bflo(v.y); acc8[j][3] += bfhi(v.y);
      acc8[j][4] += bflo(v.z); acc8[j][5] += bfhi(v.z);
      acc8[j][6] += bflo(v.w); acc8[j][7] += bfhi(v.w);
    }
  }
  // reduce across the 4 slots; lanes 0..15 write 16 B each
#pragma unroll
  for (int j = 0; j < 8; ++j) {
    float inv = 1.0f / fmaxf((float)c[j], 1.0f);
    unsigned o[4];
#pragma unroll
    for (int t = 0; t < 4; ++t) {
      float a = acc8[j][2 * t], b = acc8[j][2 * t + 1];
      a += __shfl_xor(a, 16, 64); b += __shfl_xor(b, 16, 64);
      a += __shfl_xor(a, 32, 64); b += __shfl_xor(b, 32, 64);
      o[t] = pack2(a * inv, b * inv);
    }
    if (slot == 0)
      *(uint4*)&sa[rbase + j][FD + fq * 8] = make_uint4(o[0], o[1], o[2], o[3]);
  }
  __syncthreads();

  // MFMA GEMM: wave -> col-tiles {2wv, 2wv+1} x row-tiles {0,1}
  int m = lane & 15, q = lane >> 4;
  f32x4 z = {0.f, 0.f, 0.f, 0.f};
  f32x4 acc[2][2] = {{z, z}, {z, z}};
  int ct0 = wv * 2;
  const bf16x8* WfV = (const bf16x8*)Wf;
#pragma unroll
  for (int kt = 0; kt < 8; ++kt) {
    bf16x8 a0 = *(const bf16x8*)&sa[m][kt * 32 + q * 8];
    bf16x8 a1 = *(const bf16x8*)&sa[16 + m][kt * 32 + q * 8];
    bf16x8 b0 = WfV[(size_t)(ct0 * 8 + kt) * 64 + lane];
    bf16x8 b1 = WfV[(size_t)((ct0 + 1) * 8 + kt) * 64 + lane];
    acc[0][0] = __builtin_amdgcn_mfma_f32_16x16x32_bf16(a0, b0, acc[0][0], 0, 0, 0);
    acc[0][1] = __builtin_amdgcn_mfma_f32_16x16x32_bf16(a0, b1, acc[0][1], 0, 0, 0);
    acc[1][0] = __builtin_amdgcn_mfma_f32_16x16x32_bf16(a1, b0, acc[1][0], 0, 0, 0);
    acc[1][1] = __builtin_amdgcn_mfma_f32_16x16x32_bf16(a1, b1, acc[1][1], 0, 0, 0);
  }

  // epilogue: C/D col = lane&15, row = q*4 + reg
#pragma unroll
  for (int rt = 0; rt < 2; ++rt) {
#pragma unroll
    for (int t = 0; t < 2; ++t) {
      int col = (ct0 + t) * 16 + m;
#pragma unroll
      for (int reg = 0; reg < 4; ++reg) {
        int gr = rowBase + rt * 16 + q * 4 + reg;
        if (gr < n) {
          float v = fmaxf(acc[rt][t][reg], 0.f);
          if (gr < split)
            outb[(size_t)gr * FD + col] = f2b(v);
          else
            outf[(size_t)gr * FD + col] = v;
        }
      }
    }
  }
}

// ---------------- temporal head (MFMA): 32 rows/block ----------------
// A-tile cols: [0:128)=f2 (bf16 input), [128:256)=p0 (later tf), [256:384)=p1
__global__ __launch_bounds__(256) void k_fuse(const unsigned* __restrict__ f2b_in,  // bf16 [num][128] as uint[.][64]
                                              const float* __restrict__ past,  // [2,num,128]
                                              const unsigned short* __restrict__ Wcf,  // [8][12][64][8]
                                              const unsigned short* __restrict__ Wtf,  // [8][8][64][8]
                                              float* __restrict__ out, int num) {
  __shared__ unsigned short sa[32][392];  // 384 + 8 pad
  __shared__ float so[32][132];
  int tid = threadIdx.x;
  int lane = tid & 63, wv = tid >> 6;
  int base = blockIdx.x * 32;

  for (int i = tid; i < 32 * 64; i += 256) {
    int r = i >> 6, cp = i & 63;
    int gr = base + r;
    unsigned uf = 0;
    float2 v0 = {0.f, 0.f}, v1 = {0.f, 0.f};
    if (gr < num) {
      uf = f2b_in[(size_t)gr * 64 + cp];
      v0 = *(const float2*)&past[(size_t)gr * FD + cp * 2];
      v1 = *(const float2*)&past[(size_t)num * FD + (size_t)gr * FD + cp * 2];
    }
    *(unsigned*)&sa[r][cp * 2]       = uf;
    *(unsigned*)&sa[r][FD + cp * 2]  = pack2(v0.x, v0.y);
    *(unsigned*)&sa[r][256 + cp * 2] = pack2(v1.x, v1.y);
  }
  __syncthreads();

  int m = lane & 15, q = lane >> 4;
  int ct0 = wv * 2;
  f32x4 z = {0.f, 0.f, 0.f, 0.f};
  const bf16x8* WcV = (const bf16x8*)Wcf;
  const bf16x8* WtV = (const bf16x8*)Wtf;

  // GEMM1: K=384
  f32x4 acc[2][2] = {{z, z}, {z, z}};
#pragma unroll
  for (int kt = 0; kt < 12; ++kt) {
    bf16x8 a0 = *(const bf16x8*)&sa[m][kt * 32 + q * 8];
    bf16x8 a1 = *(const bf16x8*)&sa[16 + m][kt * 32 + q * 8];
    bf16x8 b0 = WcV[(size_t)(ct0 * 12 + kt) * 64 + lane];
    bf16x8 b1 = WcV[(size_t)((ct0 + 1) * 12 + kt) * 64 + lane];
    acc[0][0] = __builtin_amdgcn_mfma_f32_16x16x32_bf16(a0, b0, acc[0][0], 0, 0, 0);
    acc[0][1] = __builtin_amdgcn_mfma_f32_16x16x32_bf16(a0, b1, acc[0][1], 0, 0, 0);
    acc[1][0] = __builtin_amdgcn_mfma_f32_16x16x32_bf16(a1, b0, acc[1][0], 0, 0, 0);
    acc[1][1] = __builtin_amdgcn_mfma_f32_16x16x32_bf16(a1, b1, acc[1][1], 0, 0, 0);
  }
  __syncthreads();  // all GEMM1 A-reads done before overwriting p0 region

  const float inv3 = 1.0f / 3.0f;
#pragma unroll
  for (int rt = 0; rt < 2; ++rt)
#pragma unroll
    for (int t = 0; t < 2; ++t) {
      int col = (ct0 + t) * 16 + m;
#pragma unroll
      for (int reg = 0; reg < 4; ++reg)
        sa[rt * 16 + q * 4 + reg][FD + col] = f2b(acc[rt][t][reg] * inv3);
    }
  __syncthreads();

  // GEMM2: K=256 over cols [0,256)
  f32x4 acc2[2][2] = {{z, z}, {z, z}};
#pragma unroll
  for (int kt = 0; kt < 8; ++kt) {
    bf16x8 a0 = *(const bf16x8*)&sa[m][kt * 32 + q * 8];
    bf16x8 a1 = *(const bf16x8*)&sa[16 + m][kt * 32 + q * 8];
    bf16x8 b0 = WtV[(size_t)(ct0 * 8 + kt) * 64 + lane];
    bf16x8 b1 = WtV[(size_t)((ct0 + 1) * 8 + kt) * 64 + lane];
    acc2[0][0] = __builtin_amdgcn_mfma_f32_16x16x32_bf16(a0, b0, acc2[0][0], 0, 0, 0);
    acc2[0][1] = __builtin_amdgcn_mfma_f32_16x16x32_bf16(a0, b1, acc2[0][1], 0, 0, 0);
    acc2[1][0] = __builtin_amdgcn_mfma_f32_16x16x32_bf16(a1, b0, acc2[1][0], 0, 0, 0);
    acc2[1][1] = __builtin_amdgcn_mfma_f32_16x16x32_bf16(a1, b1, acc2[1][1], 0, 0, 0);
  }

  // leaky into so
#pragma unroll
  for (int rt = 0; rt < 2; ++rt)
#pragma unroll
    for (int t = 0; t < 2; ++t) {
      int col = (ct0 + t) * 16 + m;
#pragma unroll
      for (int reg = 0; reg < 4; ++reg) {
        float v = acc2[rt][t][reg];
        so[rt * 16 + q * 4 + reg][col] = v > 0.f ? v : 0.2f * v;
      }
    }
  __syncthreads();

  // normalize: wave wv -> rows wv*8..wv*8+7; lane covers cols 2*lane, 2*lane+1
#pragma unroll
  for (int j = 0; j < 8; ++j) {
    int r = wv * 8 + j;
    float v0 = so[r][lane * 2], v1 = so[r][lane * 2 + 1];
    float ss = v0 * v0 + v1 * v1;
#pragma unroll
    for (int mk = 32; mk >= 1; mk >>= 1) ss += __shfl_xor(ss, mk, 64);
    float inv = 1.0f / fmaxf(sqrtf(ss), 1e-12f);
    int gr = base + r;
    if (gr < num) {
      float2 o = {v0 * inv, v1 * inv};
      *(float2*)&out[(size_t)gr * FD + lane * 2] = o;
    }
  }
}

extern "C" void kernel_launch(void* const* d_in, const int* in_sizes, int n_in,
                              void* d_out, int out_size, void* d_ws, size_t ws_size,
                              hipStream_t stream) {
  const float* x    = (const float*)d_in[0];
  const float* past = (const float*)d_in[1];
  const float* W1   = (const float*)d_in[2];
  const float* W2   = (const float*)d_in[3];
  const float* W0   = (const float*)d_in[4];
  const float* Wp   = (const float*)d_in[5];
  const float* WT   = (const float*)d_in[6];
  const int*   ei   = (const int*)d_in[7];

  int N   = in_sizes[0] / FD;
  int NUM = in_sizes[1] / (2 * FD);  // past is [2, NUM, 128]
  int E   = in_sizes[7] / 2;
  const int* src = ei;
  const int* dst = ei + E;
  float* out = (float*)d_out;

  int NB = (N + 255) >> BSH;  // 256-node bins

  // workspace layout
  char* p = (char*)d_ws;
  int* cnt      = (int*)p;  p += (((size_t)N * 4 + 255) & ~(size_t)255);
  int* idx      = (int*)p;  p += (size_t)N * CAP * 4;
  int* binCnt   = (int*)p;  p += MAXNB * 4;
  int* binStart = (int*)p;  p += MAXNB * 4;
  int* binCur   = (int*)p;  p += MAXNB * 4;
  uint2* binned = (uint2*)p; p += (size_t)E * 8;
  unsigned short* xb  = (unsigned short*)p; p += (size_t)(N + 1) * FD * 2;
  unsigned short* f1b = (unsigned short*)p; p += (size_t)(N + 1) * FD * 2;
  unsigned short* w1f = (unsigned short*)p; p += (size_t)8 * 8 * 64 * 8 * 2;
  unsigned short* w2f = (unsigned short*)p; p += (size_t)8 * 8 * 64 * 8 * 2;
  unsigned short* wcf = (unsigned short*)p; p += (size_t)8 * 12 * 64 * 8 * 2;
  unsigned short* wtf = (unsigned short*)p;
  unsigned short* f2b_buf = xb;  // xb is dead after layer 1; reuse for bf16 feat2

  hipMemsetAsync(binCnt, 0, MAXNB * sizeof(int), stream);

  // CSR build: hist -> scan -> binned scatter -> per-bin bucket (LDS counters)
  k_hist<<<400, 256, 0, stream>>>(src, dst, binCnt, E, N, NB);
  k_scan<<<1, 512, 0, stream>>>(binCnt, binStart, binCur, NB);
  k_binscatter<<<(E + 4095) / 4096, 256, 0, stream>>>(src, dst, binCur, binned, E, N, NB);
  k_bucket2<<<NB, 256, 0, stream>>>(binned, binStart, binCnt, cnt, idx, N);

  k_xcast<<<(N * 32 + 255) / 256, 256, 0, stream>>>((const float4*)x, xb, N * 32);
  k_prep<<<290, 64, 0, stream>>>(W1, W2, W0, Wp, Wp + FD * FD, WT,
                                 w1f, w2f, wcf, wtf,
                                 (unsigned*)(xb + (size_t)N * FD),
                                 (unsigned*)(f1b + (size_t)N * FD));

  int sageGrid = (N + 31) / 32;
  // layer 1: xb -> f1b (all rows bf16)
  k_sage<<<sageGrid, 256, 0, stream>>>((const unsigned*)xb, cnt, idx, w1f,
                                       nullptr, f1b, N, N);
  // layer 2: f1b -> rows<NUM bf16 (f2b_buf), rows>=NUM fp32 (out, final)
  k_sage<<<sageGrid, 256, 0, stream>>>((const unsigned*)f1b, cnt, idx, w2f,
                                       out, f2b_buf, N, NUM);
  // head: consumes bf16 feat2, writes fp32 rows [0,NUM) of out
  k_fuse<<<(NUM + 31) / 32, 256, 0, stream>>>((const unsigned*)f2b_buf, past,
                                              wcf, wtf, out, NUM);
}

// Round 9
// 419.559 us; speedup vs baseline: 1.0892x; 1.0892x over previous
//
#include <hip/hip_runtime.h>

#define FD 128
#define CAP 64   // max degree capacity; Binomial(1.6M,1e-5) max ~45
#define BSH 8    // bin shift: 256 nodes per bin
#define MAXNB 512
#define HB 400   // histogram blocks

typedef __attribute__((ext_vector_type(8))) short bf16x8;
typedef __attribute__((ext_vector_type(4))) float f32x4;

__device__ __forceinline__ float bflo(unsigned v) { return __uint_as_float(v << 16); }
__device__ __forceinline__ float bfhi(unsigned v) { return __uint_as_float(v & 0xffff0000u); }
__device__ __forceinline__ unsigned short f2b(float f) {  // fp32 -> bf16 RNE
  unsigned u = __float_as_uint(f);
  return (unsigned short)((u + 0x7fffu + ((u >> 16) & 1u)) >> 16);
}
__device__ __forceinline__ unsigned pack2(float x, float y) {
  return (unsigned)f2b(x) | ((unsigned)f2b(y) << 16);
}

// ---------------- k_pre: hist partials + xcast + weight repack + sentinels ----------------
// blocks [0,HB): per-block bin histogram (no atomics on global) + grid-stride x->bf16 cast
// blocks [HB, HB+73): weight frag repack, one unit per wave (290 units)
__global__ __launch_bounds__(256) void k_pre(const int* __restrict__ src,
                                             const int* __restrict__ dst,
                                             const float4* __restrict__ x,
                                             const float* __restrict__ W1,
                                             const float* __restrict__ W2,
                                             const float* __restrict__ W0,
                                             const float* __restrict__ WpA,
                                             const float* __restrict__ WpB,
                                             const float* __restrict__ WT,
                                             int* __restrict__ ph,
                                             unsigned short* __restrict__ xb,
                                             unsigned short* __restrict__ w1f,
                                             unsigned short* __restrict__ w2f,
                                             unsigned short* __restrict__ wcf,
                                             unsigned short* __restrict__ wtf,
                                             unsigned* __restrict__ sent_x,
                                             unsigned* __restrict__ sent_f,
                                             int E, int n, int NB, int total4) {
  int tid = threadIdx.x;
  int b = blockIdx.x;
  if (b < HB) {
    __shared__ int lh[MAXNB];
    for (int i = tid; i < NB; i += 256) lh[i] = 0;
    __syncthreads();
    for (int e = b * 256 + tid; e < E; e += HB * 256) {
      unsigned s = (unsigned)src[e], d = (unsigned)dst[e];
      if (s < (unsigned)n && d < (unsigned)n) atomicAdd(&lh[d >> BSH], 1);
    }
    __syncthreads();
    for (int i = tid; i < NB; i += 256) ph[b * MAXNB + i] = lh[i];
    for (int i = b * 256 + tid; i < total4; i += HB * 256) {
      float4 v = x[i];
      *(uint2*)&xb[(size_t)i * 4] = make_uint2(pack2(v.x, v.y), pack2(v.z, v.w));
    }
    return;
  }
  int lane = tid & 63;
  int u = (b - HB) * 4 + (tid >> 6);
  if (u >= 290) return;
  if (u >= 288) {  // sentinel zero rows: 128 bf16 = 64 uints
    unsigned* d = (u == 288) ? sent_x : sent_f;
    d[lane] = 0u;
    return;
  }
  const float* srcW;
  unsigned short* Wf;
  int nkt, bb;
  if (u < 64)       { srcW = W1; Wf = w1f; nkt = 8;  bb = u; }
  else if (u < 128) { srcW = W2; Wf = w2f; nkt = 8;  bb = u - 64; }
  else if (u < 224) { srcW = W0; Wf = wcf; nkt = 12; bb = u - 128; }
  else              { srcW = WT; Wf = wtf; nkt = 8;  bb = u - 224; }
  int ct = bb % 8, kt = bb / 8;
  int ktl = kt;
  if (nkt == 12) {  // K-concat of W0, Wp0, Wp1
    srcW = kt < 4 ? W0 : (kt < 8 ? WpA : WpB);
    ktl = kt & 3;
  }
  int m = lane & 15, q = lane >> 4;
  int nn = ct * 16 + m;
  int k0 = ktl * 32 + q * 8;
  unsigned short tmp[8];
#pragma unroll
  for (int j = 0; j < 8; ++j) tmp[j] = f2b(srcW[(size_t)(k0 + j) * FD + nn]);
  unsigned short* dstp = Wf + ((size_t)(ct * nkt + kt) * 64 + lane) * 8;
  *(uint4*)dstp = *(uint4*)tmp;
}

// ---------------- k_scan: sum hist partials + exclusive prefix over bins ----------------
__global__ __launch_bounds__(512) void k_scan(const int* __restrict__ ph,
                                              int* __restrict__ binCnt,
                                              int* __restrict__ binStart,
                                              int* __restrict__ binCur, int NB) {
  __shared__ int buf[512];
  int t = threadIdx.x;
  int v0 = 0;
  if (t < NB)
    for (int b = 0; b < HB; ++b) v0 += ph[b * MAXNB + t];
  buf[t] = v0;
  __syncthreads();
  for (int off = 1; off < 512; off <<= 1) {
    int v = (t >= off) ? buf[t - off] : 0;
    __syncthreads();
    buf[t] += v;
    __syncthreads();
  }
  if (t < NB) {
    binCnt[t] = v0;
    int ex = buf[t] - v0;
    binStart[t] = ex;
    binCur[t] = ex;
  }
}

// ---------------- k_binscatter: edges -> bin-contiguous pair array ----------------
__global__ __launch_bounds__(256) void k_binscatter(const int* __restrict__ src,
                                                    const int* __restrict__ dst,
                                                    int* __restrict__ binCur,
                                                    uint2* __restrict__ binned, int E, int n, int NB) {
  __shared__ int lcnt[MAXNB], lbase[MAXNB];
  const int CH = 4096;
  int e0 = blockIdx.x * CH;
  for (int i = threadIdx.x; i < NB; i += 256) lcnt[i] = 0;
  __syncthreads();
  int se[16], de[16];
#pragma unroll
  for (int k = 0; k < 16; ++k) {
    int e = e0 + k * 256 + threadIdx.x;
    int ok = e < E;
    unsigned s = ok ? (unsigned)src[e] : 0u;
    unsigned d = ok ? (unsigned)dst[e] : 0u;
    ok = ok && s < (unsigned)n && d < (unsigned)n;
    se[k] = (int)s;
    de[k] = ok ? (int)d : -1;
    if (ok) atomicAdd(&lcnt[d >> BSH], 1);
  }
  __syncthreads();
  for (int i = threadIdx.x; i < NB; i += 256) {
    int c = lcnt[i];
    lbase[i] = c ? atomicAdd(&binCur[i], c) : 0;
    lcnt[i] = 0;
  }
  __syncthreads();
#pragma unroll
  for (int k = 0; k < 16; ++k) {
    if (de[k] >= 0) {
      int b = de[k] >> BSH;
      int p = lbase[b] + atomicAdd(&lcnt[b], 1);
      binned[p] = make_uint2((unsigned)se[k], (unsigned)de[k]);
    }
  }
}

// ---------------- k_bucket2: build idx/cnt + per-bin degree sort (perm) ----------------
// Bin owns dst range exclusively -> LDS counters, zero global atomics.
// perm[bin*256 + pos] lists the bin's nodes in ascending-degree order
// (sentinel slots -> node id n), equalizing degrees within k_sage's 8-row groups.
__global__ __launch_bounds__(256) void k_bucket2(const uint2* __restrict__ binned,
                                                 const int* __restrict__ binStart,
                                                 const int* __restrict__ binCnt,
                                                 int* __restrict__ cnt,
                                                 int* __restrict__ idx,
                                                 int* __restrict__ perm, int n) {
  __shared__ int lcnt[256];
  __shared__ int dh[66];
  int t = threadIdx.x;
  int bin = blockIdx.x;
  int base = bin << BSH;
  lcnt[t] = 0;
  if (t < 66) dh[t] = 0;
  __syncthreads();
  int s0 = binStart[bin], c0 = binCnt[bin];
  for (int i = t; i < c0; i += 256) {
    uint2 pr = binned[s0 + i];
    int p = atomicAdd(&lcnt[pr.y & 255], 1);
    if (p < CAP) idx[(size_t)pr.y * CAP + p] = (int)pr.x;
  }
  __syncthreads();
  int node = base + t;
  int c = min(lcnt[t], CAP);
  if (node < n) cnt[node] = lcnt[t];
  int key = (node < n) ? c : 65;
  atomicAdd(&dh[key], 1);
  __syncthreads();
  if (t == 0) {
    int run = 0;
    for (int i = 0; i < 66; ++i) { int v = dh[i]; dh[i] = run; run += v; }
  }
  __syncthreads();
  int pos = atomicAdd(&dh[key], 1);
  perm[(size_t)base + pos] = (node < n) ? node : n;
}

// ---------------- fused gather-mean + SAGE layer (bf16 MFMA) ----------------
// hb has n+1 rows; row n is all-zero (sentinel). 32 perm-slots/block, 8/wave.
// Gather: scalar row index via readlane -> SGPR-based 256 B coalesced loads.
// Epilogue: node < split -> bf16 outb; node >= split -> fp32 outf.
__global__ __launch_bounds__(256, 4) void k_sage(const unsigned* __restrict__ hb,  // bf16 [n+1][128] as uint[.][64]
                                                 const int* __restrict__ cnt,
                                                 const int* __restrict__ idx,
                                                 const int* __restrict__ perm,
                                                 const unsigned short* __restrict__ Wf,  // [8][8][64][8]
                                                 float* __restrict__ outf,
                                                 unsigned short* __restrict__ outb,
                                                 int n, int split) {
  __shared__ unsigned short sa[32][264];
  __shared__ int sp[32];
  int tid = threadIdx.x;
  int lane = tid & 63, wv = tid >> 6;
  int rowBase = blockIdx.x * 32;

  if (tid < 32) sp[tid] = perm[rowBase + tid];
  __syncthreads();

  // stage self rows (k = 0..127); pv==n hits the zero sentinel row
  for (int i = tid; i < 32 * 64; i += 256) {
    int r = i >> 6, cp = i & 63;
    int pv = sp[r];
    *(unsigned*)&sa[r][cp * 2] = hb[(size_t)pv * 64 + cp];
  }

  // ---- branch-free gather-mean: 8 rows/wave (degree-equalized by perm) ----
  int rbase = wv * 8;
  int vidx[8], c[8];
  int maxc = 0;
#pragma unroll
  for (int j = 0; j < 8; ++j) {
    int pv = sp[rbase + j];
    int cj = (pv < n) ? min(cnt[pv], CAP) : 0;
    cj = __builtin_amdgcn_readfirstlane(cj);
    c[j] = cj;
    maxc = max(maxc, cj);
    int pvc = min(pv, n - 1);
    vidx[j] = idx[(size_t)pvc * CAP + lane];  // coalesced 256 B prefetch
  }
  float ax[8], ay[8];
#pragma unroll
  for (int j = 0; j < 8; ++j) { ax[j] = 0.f; ay[j] = 0.f; }

  for (int e = 0; e < maxc; e += 2) {
    int e1 = min(e + 1, CAP - 1);
#pragma unroll
    for (int j = 0; j < 8; ++j) {
      int s0 = __builtin_amdgcn_readlane(vidx[j], e);   // SGPR broadcast
      int s1 = __builtin_amdgcn_readlane(vidx[j], e1);
      s0 = (e < c[j]) ? s0 : n;       // scalar select -> sentinel zero row
      s1 = (e + 1 < c[j]) ? s1 : n;
      unsigned v0 = hb[(size_t)s0 * 64 + lane];  // straight-line: 16 loads in flight
      unsigned v1 = hb[(size_t)s1 * 64 + lane];
      ax[j] += bflo(v0) + bflo(v1);
      ay[j] += bfhi(v0) + bfhi(v1);
    }
  }
#pragma unroll
  for (int j = 0; j < 8; ++j) {
    float inv = 1.0f / fmaxf((float)c[j], 1.0f);
    *(unsigned*)&sa[rbase + j][FD + lane * 2] = pack2(ax[j] * inv, ay[j] * inv);
  }
  __syncthreads();

  // MFMA GEMM: wave -> col-tiles {2wv, 2wv+1} x row-tiles {0,1}
  int m = lane & 15, q = lane >> 4;
  f32x4 z = {0.f, 0.f, 0.f, 0.f};
  f32x4 acc[2][2] = {{z, z}, {z, z}};
  int ct0 = wv * 2;
  const bf16x8* WfV = (const bf16x8*)Wf;
#pragma unroll
  for (int kt = 0; kt < 8; ++kt) {
    bf16x8 a0 = *(const bf16x8*)&sa[m][kt * 32 + q * 8];
    bf16x8 a1 = *(const bf16x8*)&sa[16 + m][kt * 32 + q * 8];
    bf16x8 b0 = WfV[(size_t)(ct0 * 8 + kt) * 64 + lane];
    bf16x8 b1 = WfV[(size_t)((ct0 + 1) * 8 + kt) * 64 + lane];
    acc[0][0] = __builtin_amdgcn_mfma_f32_16x16x32_bf16(a0, b0, acc[0][0], 0, 0, 0);
    acc[0][1] = __builtin_amdgcn_mfma_f32_16x16x32_bf16(a0, b1, acc[0][1], 0, 0, 0);
    acc[1][0] = __builtin_amdgcn_mfma_f32_16x16x32_bf16(a1, b0, acc[1][0], 0, 0, 0);
    acc[1][1] = __builtin_amdgcn_mfma_f32_16x16x32_bf16(a1, b1, acc[1][1], 0, 0, 0);
  }

  // epilogue: C/D col = lane&15, row = q*4 + reg; route by node id
#pragma unroll
  for (int rt = 0; rt < 2; ++rt) {
#pragma unroll
    for (int t = 0; t < 2; ++t) {
      int col = (ct0 + t) * 16 + m;
#pragma unroll
      for (int reg = 0; reg < 4; ++reg) {
        int pv = sp[rt * 16 + q * 4 + reg];
        if (pv < n) {
          float v = fmaxf(acc[rt][t][reg], 0.f);
          if (pv < split)
            outb[(size_t)pv * FD + col] = f2b(v);
          else
            outf[(size_t)pv * FD + col] = v;
        }
      }
    }
  }
}

// ---------------- temporal head (MFMA): 32 rows/block ----------------
// A-tile cols: [0:128)=f2 (bf16 input), [128:256)=p0 (later tf), [256:384)=p1
__global__ __launch_bounds__(256) void k_fuse(const unsigned* __restrict__ f2b_in,  // bf16 [num][128] as uint[.][64]
                                              const float* __restrict__ past,  // [2,num,128]
                                              const unsigned short* __restrict__ Wcf,  // [8][12][64][8]
                                              const unsigned short* __restrict__ Wtf,  // [8][8][64][8]
                                              float* __restrict__ out, int num) {
  __shared__ unsigned short sa[32][392];  // 384 + 8 pad
  __shared__ float so[32][132];
  int tid = threadIdx.x;
  int lane = tid & 63, wv = tid >> 6;
  int base = blockIdx.x * 32;

  for (int i = tid; i < 32 * 64; i += 256) {
    int r = i >> 6, cp = i & 63;
    int gr = base + r;
    unsigned uf = 0;
    float2 v0 = {0.f, 0.f}, v1 = {0.f, 0.f};
    if (gr < num) {
      uf = f2b_in[(size_t)gr * 64 + cp];
      v0 = *(const float2*)&past[(size_t)gr * FD + cp * 2];
      v1 = *(const float2*)&past[(size_t)num * FD + (size_t)gr * FD + cp * 2];
    }
    *(unsigned*)&sa[r][cp * 2]       = uf;
    *(unsigned*)&sa[r][FD + cp * 2]  = pack2(v0.x, v0.y);
    *(unsigned*)&sa[r][256 + cp * 2] = pack2(v1.x, v1.y);
  }
  __syncthreads();

  int m = lane & 15, q = lane >> 4;
  int ct0 = wv * 2;
  f32x4 z = {0.f, 0.f, 0.f, 0.f};
  const bf16x8* WcV = (const bf16x8*)Wcf;
  const bf16x8* WtV = (const bf16x8*)Wtf;

  // GEMM1: K=384
  f32x4 acc[2][2] = {{z, z}, {z, z}};
#pragma unroll
  for (int kt = 0; kt < 12; ++kt) {
    bf16x8 a0 = *(const bf16x8*)&sa[m][kt * 32 + q * 8];
    bf16x8 a1 = *(const bf16x8*)&sa[16 + m][kt * 32 + q * 8];
    bf16x8 b0 = WcV[(size_t)(ct0 * 12 + kt) * 64 + lane];
    bf16x8 b1 = WcV[(size_t)((ct0 + 1) * 12 + kt) * 64 + lane];
    acc[0][0] = __builtin_amdgcn_mfma_f32_16x16x32_bf16(a0, b0, acc[0][0], 0, 0, 0);
    acc[0][1] = __builtin_amdgcn_mfma_f32_16x16x32_bf16(a0, b1, acc[0][1], 0, 0, 0);
    acc[1][0] = __builtin_amdgcn_mfma_f32_16x16x32_bf16(a1, b0, acc[1][0], 0, 0, 0);
    acc[1][1] = __builtin_amdgcn_mfma_f32_16x16x32_bf16(a1, b1, acc[1][1], 0, 0, 0);
  }
  __syncthreads();  // all GEMM1 A-reads done before overwriting p0 region

  const float inv3 = 1.0f / 3.0f;
#pragma unroll
  for (int rt = 0; rt < 2; ++rt)
#pragma unroll
    for (int t = 0; t < 2; ++t) {
      int col = (ct0 + t) * 16 + m;
#pragma unroll
      for (int reg = 0; reg < 4; ++reg)
        sa[rt * 16 + q * 4 + reg][FD + col] = f2b(acc[rt][t][reg] * inv3);
    }
  __syncthreads();

  // GEMM2: K=256 over cols [0,256)
  f32x4 acc2[2][2] = {{z, z}, {z, z}};
#pragma unroll
  for (int kt = 0; kt < 8; ++kt) {
    bf16x8 a0 = *(const bf16x8*)&sa[m][kt * 32 + q * 8];
    bf16x8 a1 = *(const bf16x8*)&sa[16 + m][kt * 32 + q * 8];
    bf16x8 b0 = WtV[(size_t)(ct0 * 8 + kt) * 64 + lane];
    bf16x8 b1 = WtV[(size_t)((ct0 + 1) * 8 + kt) * 64 + lane];
    acc2[0][0] = __builtin_amdgcn_mfma_f32_16x16x32_bf16(a0, b0, acc2[0][0], 0, 0, 0);
    acc2[0][1] = __builtin_amdgcn_mfma_f32_16x16x32_bf16(a0, b1, acc2[0][1], 0, 0, 0);
    acc2[1][0] = __builtin_amdgcn_mfma_f32_16x16x32_bf16(a1, b0, acc2[1][0], 0, 0, 0);
    acc2[1][1] = __builtin_amdgcn_mfma_f32_16x16x32_bf16(a1, b1, acc2[1][1], 0, 0, 0);
  }

  // leaky into so
#pragma unroll
  for (int rt = 0; rt < 2; ++rt)
#pragma unroll
    for (int t = 0; t < 2; ++t) {
      int col = (ct0 + t) * 16 + m;
#pragma unroll
      for (int reg = 0; reg < 4; ++reg) {
        float v = acc2[rt][t][reg];
        so[rt * 16 + q * 4 + reg][col] = v > 0.f ? v : 0.2f * v;
      }
    }
  __syncthreads();

  // normalize: wave wv -> rows wv*8..wv*8+7; lane covers cols 2*lane, 2*lane+1
#pragma unroll
  for (int j = 0; j < 8; ++j) {
    int r = wv * 8 + j;
    float v0 = so[r][lane * 2], v1 = so[r][lane * 2 + 1];
    float ss = v0 * v0 + v1 * v1;
#pragma unroll
    for (int mk = 32; mk >= 1; mk >>= 1) ss += __shfl_xor(ss, mk, 64);
    float inv = 1.0f / fmaxf(sqrtf(ss), 1e-12f);
    int gr = base + r;
    if (gr < num) {
      float2 o = {v0 * inv, v1 * inv};
      *(float2*)&out[(size_t)gr * FD + lane * 2] = o;
    }
  }
}

extern "C" void kernel_launch(void* const* d_in, const int* in_sizes, int n_in,
                              void* d_out, int out_size, void* d_ws, size_t ws_size,
                              hipStream_t stream) {
  const float* x    = (const float*)d_in[0];
  const float* past = (const float*)d_in[1];
  const float* W1   = (const float*)d_in[2];
  const float* W2   = (const float*)d_in[3];
  const float* W0   = (const float*)d_in[4];
  const float* Wp   = (const float*)d_in[5];
  const float* WT   = (const float*)d_in[6];
  const int*   ei   = (const int*)d_in[7];

  int N   = in_sizes[0] / FD;
  int NUM = in_sizes[1] / (2 * FD);  // past is [2, NUM, 128]
  int E   = in_sizes[7] / 2;
  const int* src = ei;
  const int* dst = ei + E;
  float* out = (float*)d_out;

  int NB = (N + 255) >> BSH;  // 256-node bins

  // workspace layout
  char* p = (char*)d_ws;
  int* cnt      = (int*)p;  p += (((size_t)N * 4 + 255) & ~(size_t)255);
  int* idx      = (int*)p;  p += (size_t)N * CAP * 4;
  int* binCnt   = (int*)p;  p += MAXNB * 4;
  int* binStart = (int*)p;  p += MAXNB * 4;
  int* binCur   = (int*)p;  p += MAXNB * 4;
  int* ph       = (int*)p;  p += (size_t)HB * MAXNB * 4;
  int* perm     = (int*)p;  p += (size_t)MAXNB * 256 * 4;
  uint2* binned = (uint2*)p; p += (size_t)E * 8;
  unsigned short* xb  = (unsigned short*)p; p += (size_t)(N + 1) * FD * 2;
  unsigned short* f1b = (unsigned short*)p; p += (size_t)(N + 1) * FD * 2;
  unsigned short* w1f = (unsigned short*)p; p += (size_t)8 * 8 * 64 * 8 * 2;
  unsigned short* w2f = (unsigned short*)p; p += (size_t)8 * 8 * 64 * 8 * 2;
  unsigned short* wcf = (unsigned short*)p; p += (size_t)8 * 12 * 64 * 8 * 2;
  unsigned short* wtf = (unsigned short*)p;
  unsigned short* f2b_buf = xb;  // xb dead after layer 1; reuse for bf16 feat2

  // 1) hist partials + xcast + wpack + sentinels (no memsets needed)
  k_pre<<<HB + 73, 256, 0, stream>>>(src, dst, (const float4*)x,
                                     W1, W2, W0, Wp, Wp + FD * FD, WT,
                                     ph, xb, w1f, w2f, wcf, wtf,
                                     (unsigned*)(xb + (size_t)N * FD),
                                     (unsigned*)(f1b + (size_t)N * FD),
                                     E, N, NB, N * 32);
  // 2) bin offsets
  k_scan<<<1, 512, 0, stream>>>(ph, binCnt, binStart, binCur, NB);
  // 3) bin-contiguous edge pairs
  k_binscatter<<<(E + 4095) / 4096, 256, 0, stream>>>(src, dst, binCur, binned, E, N, NB);
  // 4) CSR buckets + degree-sorted perm
  k_bucket2<<<NB, 256, 0, stream>>>(binned, binStart, binCnt, cnt, idx, perm, N);

  int sageGrid = NB * 8;  // 32 perm slots per block
  // 5) layer 1: xb -> f1b (all rows bf16)
  k_sage<<<sageGrid, 256, 0, stream>>>((const unsigned*)xb, cnt, idx, perm, w1f,
                                       nullptr, f1b, N, N);
  // 6) layer 2: rows<NUM bf16 (f2b_buf), rows>=NUM fp32 (out, final)
  k_sage<<<sageGrid, 256, 0, stream>>>((const unsigned*)f1b, cnt, idx, perm, w2f,
                                       out, f2b_buf, N, NUM);
  // 7) head: bf16 feat2 -> fp32 rows [0,NUM) of out
  k_fuse<<<(NUM + 31) / 32, 256, 0, stream>>>((const unsigned*)f2b_buf, past,
                                              wcf, wtf, out, NUM);
}